// Round 10
// baseline (294140.479 us; speedup 1.0000x reference)
//
#include <hip/hip_runtime.h>
#include <math.h>

// HierarchicalRecursiveTRM on MI355X — round 10 (round 9 + fp16 type fix).
// Architecture: kill cross-CU exchange on the critical path.
//   blocks 0..15  : GRU WG, one batch each (1024 thr). Weights f16x2 in VGPRs.
//                   Publishes h_t as round-7-proven tagged u64 words into a
//                   32-slot ring (relaxed agent stores), with progress-based
//                   backpressure.
//   blocks 16..31 : refine WG, one batch each. ALL refinement weights f16x2 in
//                   VGPRs (~320 regs/thread). All 12 stages/t are intra-CU:
//                   LDS pre-activation exchange + s_barrier. One cross-CU poll
//                   per t (GRU runs ~7x ahead -> tag already visible).
// Cross-CU protocol facts (rounds 3-8): relaxed agent ld/st tagged words work;
// ~2.6us visibility => only 1 poll per t can afford it; atomics slower.

#define NB   16
#define SEQ  4096
#define RING 32

typedef unsigned long long u64;

__device__ __forceinline__ float fexp(float v){ return __builtin_amdgcn_exp2f(v*1.44269504089f); }
__device__ __forceinline__ float sigf(float v){ return __builtin_amdgcn_rcpf(1.f + fexp(-v)); }
__device__ __forceinline__ float ftanh(float v){ return 2.f*sigf(2.f*v) - 1.f; }

__device__ __forceinline__ void stw(u64* p, u64 v){
  __hip_atomic_store(p, v, __ATOMIC_RELAXED, __HIP_MEMORY_SCOPE_AGENT);
}
__device__ __forceinline__ u64 ldw(const u64* p){
  return __hip_atomic_load(p, __ATOMIC_RELAXED, __HIP_MEMORY_SCOPE_AGENT);
}
__device__ __forceinline__ u64 packw(float v, unsigned tag){
  return ((u64)tag<<32) | (u64)__float_as_uint(v);
}

// Raw WG barrier: LDS ordering only (global stores fire-and-forget).
#define WGBAR() asm volatile("s_waitcnt lgkmcnt(0)\n\ts_barrier" ::: "memory")

// f16x2 pack / dot helpers. cvt_pkrtz returns __fp16-vec; fdot2 takes
// _Float16-vec — union both views of the same 32-bit word.
typedef _Float16 h2f __attribute__((ext_vector_type(2)));
typedef __fp16   h2p __attribute__((ext_vector_type(2)));
union H2U { h2f f; h2p p; unsigned u; };

__device__ __forceinline__ unsigned pk2(float lo, float hi){
  H2U t; t.p = __builtin_amdgcn_cvt_pkrtz(lo, hi); return t.u;
}
__device__ __forceinline__ float fd2(unsigned w, unsigned a, float c){
  H2U W, A; W.u = w; A.u = a;
  return __builtin_amdgcn_fdot2(W.f, A.f, c, false);
}

extern "C" __global__ __launch_bounds__(1024)
void trm_kernel(const float* __restrict__ x,   const float* __restrict__ h0,
                const float* __restrict__ wih, const float* __restrict__ whh,
                const float* __restrict__ bih, const float* __restrict__ bhh,
                const float* __restrict__ Lgw, const float* __restrict__ Lgb,
                const float* __restrict__ Ltw, const float* __restrict__ Ltb,
                const float* __restrict__ Luw, const float* __restrict__ Lub,
                const float* __restrict__ Hgw, const float* __restrict__ Hgb,
                const float* __restrict__ Htw, const float* __restrict__ Htb,
                const float* __restrict__ Huw, const float* __restrict__ Hub,
                float* __restrict__ out, u64* __restrict__ ring)
{
  const int tid  = threadIdx.x;
  const bool isG = (blockIdx.x < NB);
  const int b    = isG ? blockIdx.x : blockIdx.x - NB;
  u64* ringb = ring + (size_t)b*(RING*256);
  u64* prog  = ring + (size_t)NB*(RING*256) + b;

  // LDS: packed f16x2 activation vectors + f32 state + preacts + biases
  __shared__ __align__(16) unsigned oh2[128];   // refine: o
  __shared__ __align__(16) unsigned zh2[128];   // refine: zH
  __shared__ __align__(16) unsigned zl2[128];   // refine: zL
  __shared__ __align__(16) unsigned xh2[128];   // GRU: x_t
  __shared__ __align__(16) unsigned hh2[128];   // GRU: h
  __shared__ float st32[256];                   // f32 state: o (refine) / h (GRU)
  __shared__ __align__(16) float pre[1024];
  __shared__ float b0[256], b1[256], b2[256], b3[256], b4[256], b5[256];

  if (isG){
    // ================= GRU role =================
    // pass1: unit u=tid>>1 in [0,512): wih/whh row u (r rows 0..255, z rows 256..511),
    //        half h=tid&1: 0 -> x-matrix (wih), 1 -> h-matrix (whh). K=256 each.
    // pass2: unit u: u<256 xn row (wih row 512+u), else hn row (whh row 256+u);
    //        half h: K-slice [h*128, h*128+128).
    unsigned wrz[128], wn[64];
    {
      const int u = tid>>1, h = tid&1;
      const float2* s1 = (const float2*)((h ? whh : wih) + (size_t)u*256);
      #pragma unroll
      for (int i=0;i<128;i++){ float2 f = s1[i]; wrz[i] = pk2(f.x, f.y); }
      const float2* s2 = (const float2*)(((u<256) ? wih + (size_t)(512+u)*256
                                                  : whh + (size_t)(256+u)*256) + h*128);
      #pragma unroll
      for (int i=0;i<64;i++){ float2 f = s2[i]; wn[i] = pk2(f.x, f.y); }
    }
    if (tid < 256){
      b0[tid] = bih[tid]       + bhh[tid];        // bR
      b1[tid] = bih[256+tid]   + bhh[256+tid];    // bZ
      b2[tid] = bih[512+tid];                     // bX (xn)
      b3[tid] = bhh[512+tid];                     // bN (hn)
      const float hv = h0[b*256 + tid];
      st32[tid] = hv;
      const float ho = __shfl_xor(hv, 1);
      if (!(tid&1)) hh2[tid>>1] = pk2(hv, ho);
      const float xv = x[((size_t)b*SEQ + 0)*256 + tid];
      const float xo = __shfl_xor(xv, 1);
      if (!(tid&1)) xh2[tid>>1] = pk2(xv, xo);
    }
    __syncthreads();

    long prog_seen = 0;
    #pragma unroll 1
    for (int t=0; t<SEQ; ++t){
      { // pass1: r,z preacts (K=512 over [x|h])
        const int u = tid>>1, h = tid&1;
        const unsigned* A = h ? hh2 : xh2;
        float a0=0.f,a1=0.f,a2=0.f,a3=0.f;
        #pragma unroll
        for (int i=0;i<32;i++){
          uint4 av = *(const uint4*)(A + i*4);
          a0 = fd2(wrz[4*i+0], av.x, a0);
          a1 = fd2(wrz[4*i+1], av.y, a1);
          a2 = fd2(wrz[4*i+2], av.z, a2);
          a3 = fd2(wrz[4*i+3], av.w, a3);
        }
        float a = (a0+a1)+(a2+a3);
        a += __shfl_xor(a, 1);
        if (!h) pre[u] = a;                      // [0..255]=r, [256..511]=z
      }
      { // pass2: xn,hn preacts (K=256)
        const int u = tid>>1, h = tid&1;
        const unsigned* A = ((u<256) ? xh2 : hh2) + h*64;
        float a0=0.f,a1=0.f,a2=0.f,a3=0.f;
        #pragma unroll
        for (int i=0;i<16;i++){
          uint4 av = *(const uint4*)(A + i*4);
          a0 = fd2(wn[4*i+0], av.x, a0);
          a1 = fd2(wn[4*i+1], av.y, a1);
          a2 = fd2(wn[4*i+2], av.z, a2);
          a3 = fd2(wn[4*i+3], av.w, a3);
        }
        float a = (a0+a1)+(a2+a3);
        a += __shfl_xor(a, 1);
        if (!h) pre[512+u] = a;                  // [512..767]=xn, [768..1023]=hn
      }
      // backpressure: don't overwrite a ring slot the consumer hasn't read
      if (tid==0 && t >= RING-8){
        const long need = (long)t - (RING-8);
        while (prog_seen < need){
          prog_seen = (long)ldw(prog);
          if (prog_seen < need) __builtin_amdgcn_s_sleep(32);
        }
      }
      WGBAR();
      if (tid < 256){
        const float rg = sigf (pre[tid]       + b0[tid]);
        const float zg = sigf (pre[256+tid]   + b1[tid]);
        const float ng = ftanh(pre[512+tid]   + b2[tid] + rg*(pre[768+tid] + b3[tid]));
        const float hv = (1.f-zg)*ng + zg*st32[tid];
        st32[tid] = hv;
        const float ho = __shfl_xor(hv, 1);
        if (!(tid&1)) hh2[tid>>1] = pk2(hv, ho);
        stw(&ringb[(size_t)(t&(RING-1))*256 + tid], packw(hv, (unsigned)(t+1)));
        if (t+1 < SEQ){
          const float xv = x[((size_t)b*SEQ + (t+1))*256 + tid];
          const float xo = __shfl_xor(xv, 1);
          if (!(tid&1)) xh2[tid>>1] = pk2(xv, xo);
        }
        if (t == SEQ-1) out[(size_t)NB*SEQ*256 + b*256 + tid] = hv;
      }
      WGBAR();
    }
  } else {
    // ================= refine role =================
    // C matrices: unit u=tid>>1 in [0,512): u<256 gate row u, else tanh row u-256;
    //             half h=tid&1: K-slice [h*256, h*256+256) of [o | hid].
    // U matrices: row r=tid>>2, sub=tid&3: K-slice [sub*64, sub*64+64).
    unsigned wcl[128], wch[128], wul[32], wuh[32];
    {
      const int u = tid>>1, h = tid&1, row = u & 255;
      const float2* sl = (const float2*)(((u<256) ? Lgw : Ltw) + (size_t)row*512 + h*256);
      const float2* sh = (const float2*)(((u<256) ? Hgw : Htw) + (size_t)row*512 + h*256);
      #pragma unroll
      for (int i=0;i<128;i++){
        float2 f = sl[i]; wcl[i] = pk2(f.x, f.y);
        float2 g = sh[i]; wch[i] = pk2(g.x, g.y);
      }
      const int r = tid>>2, sub = tid&3;
      const float2* su = (const float2*)(Luw + (size_t)r*256 + sub*64);
      const float2* sv = (const float2*)(Huw + (size_t)r*256 + sub*64);
      #pragma unroll
      for (int i=0;i<32;i++){
        float2 f = su[i]; wul[i] = pk2(f.x, f.y);
        float2 g = sv[i]; wuh[i] = pk2(g.x, g.y);
      }
    }
    if (tid < 256){
      b0[tid]=Lgb[tid]; b1[tid]=Ltb[tid];
      b2[tid]=Hgb[tid]; b3[tid]=Htb[tid];
      b4[tid]=Lub[tid]; b5[tid]=Hub[tid];
    }
    if (tid < 128){ zh2[tid] = 0u; zl2[tid] = 0u; }
    __syncthreads();

    auto CST = [&](const unsigned (&W)[128], const float* bg, const float* bt,
                   const unsigned* hid2, bool wout, int t){
      {
        const int u = tid>>1, h = tid&1;
        const unsigned* A = h ? hid2 : oh2;
        float a0=0.f,a1=0.f,a2=0.f,a3=0.f;
        #pragma unroll
        for (int i=0;i<32;i++){
          uint4 av = *(const uint4*)(A + i*4);
          a0 = fd2(W[4*i+0], av.x, a0);
          a1 = fd2(W[4*i+1], av.y, a1);
          a2 = fd2(W[4*i+2], av.z, a2);
          a3 = fd2(W[4*i+3], av.w, a3);
        }
        float a = (a0+a1)+(a2+a3);
        a += __shfl_xor(a, 1);
        if (!h) pre[u] = a;                      // [0..255]=gate, [256..511]=tanh
      }
      WGBAR();
      if (tid < 256){
        const float g  = sigf (pre[tid]     + bg[tid]);
        const float tt = ftanh(pre[256+tid] + bt[tid]);
        const float o  = g*tt + (1.f-g)*st32[tid];
        st32[tid] = o;
        const float oo = __shfl_xor(o, 1);
        if (!(tid&1)) oh2[tid>>1] = pk2(o, oo);
        if (wout) out[((size_t)b*SEQ + t)*256 + tid] = o;
      }
      WGBAR();
    };

    auto UST = [&](const unsigned (&W)[32], const float* bu, unsigned* dst2){
      {
        const int r = tid>>2, sub = tid&3;
        const unsigned* A = oh2 + sub*32;
        float a0=0.f,a1=0.f,a2=0.f,a3=0.f;
        #pragma unroll
        for (int i=0;i<8;i++){
          uint4 av = *(const uint4*)(A + i*4);
          a0 = fd2(W[4*i+0], av.x, a0);
          a1 = fd2(W[4*i+1], av.y, a1);
          a2 = fd2(W[4*i+2], av.z, a2);
          a3 = fd2(W[4*i+3], av.w, a3);
        }
        float a = (a0+a1)+(a2+a3);
        a += __shfl_xor(a, 1);
        a += __shfl_xor(a, 2);
        if (sub==0) pre[r] = a;
      }
      WGBAR();
      if (tid < 256){
        const float d  = ftanh(pre[tid] + bu[tid]);
        const float dd = __shfl_xor(d, 1);
        if (!(tid&1)) dst2[tid>>1] = pk2(d, dd);
      }
      WGBAR();
    };

    #pragma unroll 1
    for (int t=0; t<SEQ; ++t){
      // one cross-CU poll per t: base_out[t] from the GRU WG (tag = t+1)
      if (tid < 256){
        u64* p = &ringb[(size_t)(t&(RING-1))*256 + tid];
        const unsigned tg = (unsigned)(t+1);
        u64 w;
        for(;;){
          w = ldw(p);
          if ((unsigned)(w>>32) >= tg) break;
          __builtin_amdgcn_s_sleep(1);
        }
        const float val = __uint_as_float((unsigned)w);
        st32[tid] = val;
        const float vo = __shfl_xor(val, 1);
        if (!(tid&1)) oh2[tid>>1] = pk2(val, vo);
      }
      WGBAR();
      if (tid==0) stw(prog, (u64)(t+1));   // consumed slot t
      #pragma unroll 1
      for (int c=0;c<2;c++){
        #pragma unroll 1
        for (int l=0;l<3;l++) CST(wcl, b0, b1, zh2, false, t);
        UST(wul, b4, zl2);
        CST(wch, b2, b3, zl2, (c==1), t);
        UST(wuh, b5, zh2);
      }
    }
  }
}

extern "C" void kernel_launch(void* const* d_in, const int* in_sizes, int n_in,
                              void* d_out, int out_size, void* d_ws, size_t ws_size,
                              hipStream_t stream)
{
  // ws: per-batch 32-slot tagged h rings (16 x 32 x 256 u64 = 1MB) + prog[16].
  // Zeroed every launch (tags start below 1; harness poisons 0xAA once).
  const size_t ring_words = (size_t)NB*RING*256 + NB;
  (void)hipMemsetAsync(d_ws, 0, ring_words*sizeof(u64), stream);
  u64* ring = (u64*)d_ws;

  dim3 grid(2*NB), block(1024);
  hipLaunchKernelGGL(trm_kernel, grid, block, 0, stream,
    (const float*)d_in[0],  (const float*)d_in[1],
    (const float*)d_in[2],  (const float*)d_in[3],
    (const float*)d_in[4],  (const float*)d_in[5],
    (const float*)d_in[6],  (const float*)d_in[7],
    (const float*)d_in[8],  (const float*)d_in[9],
    (const float*)d_in[10], (const float*)d_in[11],
    (const float*)d_in[12], (const float*)d_in[13],
    (const float*)d_in[14], (const float*)d_in[15],
    (const float*)d_in[16], (const float*)d_in[17],
    (float*)d_out, ring);
}

// Round 11
// 97885.852 us; speedup vs baseline: 3.0049x; 3.0049x over previous
//
#include <hip/hip_runtime.h>
#include <math.h>

// HierarchicalRecursiveTRM on MI355X — round 11.
// Base = round 7 (proven 139ms): 8 teams x (2 batches, 32 WGs), f32 weights in
// LDS (1/32 rows per WG), tag-embedded u64 exchange words, relaxed-agent-load
// polling, raw s_barrier+lgkmcnt WG barriers.
// Changes (one mechanism: exchange latency):
//  1. Producer publishes via NO-RETURN atomic_exchange (commits at MALL atomic
//     unit, ~220ns per round-1 measurement) instead of plain store (which
//     drains to DRAM, ~2.6us visibility per rounds 3/7 counters).
//  2. Exchange payload = post-activation f16 pair packed with tag:
//     C-cell: (g, T) per (b,n); GRU: (n, z) per (b,n); U: (v_b0, v_b1) per n.
//     Producer lanes (16/WG) apply bias+sigmoid/tanh; consumers reconstruct
//     state in f32 (h, o never quantized; zH/zL regenerated each stage).
//  3. out[] written by j==0 WGs only (cuts 32x duplicate HBM writes).

#define NB   16
#define SEQ  4096
#define TEAMS 8
#define WPT  32
#define BPT  2
#define NTH  256

typedef unsigned long long u64;

__device__ __forceinline__ float fexp(float v){ return __builtin_amdgcn_exp2f(v*1.44269504089f); }
__device__ __forceinline__ float sigf(float v){ return __builtin_amdgcn_rcpf(1.f + fexp(-v)); }
__device__ __forceinline__ float ftanh(float v){ return 2.f*sigf(2.f*v) - 1.f; }

// producer: no-return atomic swap — commits at the coherence-point atomic unit
__device__ __forceinline__ void swpw(u64* p, u64 v){
  (void)__hip_atomic_exchange(p, v, __ATOMIC_RELAXED, __HIP_MEMORY_SCOPE_AGENT);
}
// consumer: relaxed agent load (round-3/7-proven polling primitive)
__device__ __forceinline__ u64 ldw(const u64* p){
  return __hip_atomic_load(p, __ATOMIC_RELAXED, __HIP_MEMORY_SCOPE_AGENT);
}

// f16x2 pack/unpack (cvt_pkrtz returns __fp16-vec; keep both views)
typedef _Float16 h2f __attribute__((ext_vector_type(2)));
typedef __fp16   h2p __attribute__((ext_vector_type(2)));
union H2U { h2f f; h2p p; unsigned u; };
__device__ __forceinline__ unsigned pk2(float lo, float hi){
  H2U t; t.p = __builtin_amdgcn_cvt_pkrtz(lo, hi); return t.u;
}
__device__ __forceinline__ float2 upk2(unsigned w){
  H2U t; t.u = w; float2 r; r.x = (float)t.f.x; r.y = (float)t.f.y; return r;
}
__device__ __forceinline__ u64 packh(float lo, float hi, unsigned tag){
  return ((u64)tag<<32) | (u64)pk2(lo, hi);
}

// Raw WG barrier: LDS ordering only, no vmcnt drain (swaps fly free).
#define WGBAR() asm volatile("s_waitcnt lgkmcnt(0)\n\ts_barrier" ::: "memory")

extern "C" __global__ __launch_bounds__(NTH, 1)
void trm_kernel(const float* __restrict__ x,   const float* __restrict__ h0,
                const float* __restrict__ wih, const float* __restrict__ whh,
                const float* __restrict__ bih, const float* __restrict__ bhh,
                const float* __restrict__ Lgw, const float* __restrict__ Lgb,
                const float* __restrict__ Ltw, const float* __restrict__ Ltb,
                const float* __restrict__ Luw, const float* __restrict__ Lub,
                const float* __restrict__ Hgw, const float* __restrict__ Hgb,
                const float* __restrict__ Htw, const float* __restrict__ Htb,
                const float* __restrict__ Huw, const float* __restrict__ Hub,
                float* __restrict__ out, u64* __restrict__ act_base)
{
  const int team = blockIdx.x & (TEAMS-1);
  const int j    = blockIdx.x / TEAMS;       // 0..31 slice id within team
  const int tid  = threadIdx.x;

  __shared__ float wgRZ[16][520];
  __shared__ float wgX[8][264];
  __shared__ float wgN[8][264];
  __shared__ float wclG[8][520], wclT[8][520];
  __shared__ float wchG[8][520], wchT[8][520];
  __shared__ float wul[8][264],  wuh[8][264];
  __shared__ float xst [BPT][256];
  __shared__ float st_o [BPT][256];
  __shared__ float st_zh[BPT][256];
  __shared__ float st_zl[BPT][256];
  __shared__ float st_h [BPT][256];
  __shared__ float exvA[16][2], exvB[16][2];   // per-stage pre-activation relay
  __shared__ float bR[8],bZ[8],bX[8],bN[8],bCLg[8],bCLt[8],bCHg[8],bCHt[8],bUL[8],bUH[8];

  // ---------- one-time weight staging ----------
  {
    const int k = tid;
    for (int r=0;r<8;r++){
      const int nr = j*8+r;
      wgRZ[r][k]       = wih[(size_t)nr*256+k];
      wgRZ[r][256+k]   = whh[(size_t)nr*256+k];
      wgRZ[8+r][k]     = wih[(size_t)(256+nr)*256+k];
      wgRZ[8+r][256+k] = whh[(size_t)(256+nr)*256+k];
      wgX[r][k] = wih[(size_t)(512+nr)*256+k];
      wgN[r][k] = whh[(size_t)(512+nr)*256+k];
      wclG[r][k] = Lgw[(size_t)nr*512+k];  wclG[r][256+k] = Lgw[(size_t)nr*512+256+k];
      wclT[r][k] = Ltw[(size_t)nr*512+k];  wclT[r][256+k] = Ltw[(size_t)nr*512+256+k];
      wchG[r][k] = Hgw[(size_t)nr*512+k];  wchG[r][256+k] = Hgw[(size_t)nr*512+256+k];
      wchT[r][k] = Htw[(size_t)nr*512+k];  wchT[r][256+k] = Htw[(size_t)nr*512+256+k];
      wul[r][k] = Luw[(size_t)nr*256+k];
      wuh[r][k] = Huw[(size_t)nr*256+k];
    }
    if (tid<8){
      const int nr = j*8+tid;
      bR[tid]  = bih[nr]     + bhh[nr];
      bZ[tid]  = bih[256+nr] + bhh[256+nr];
      bX[tid]  = bih[512+nr];
      bN[tid]  = bhh[512+nr];
      bCLg[tid]= Lgb[nr];  bCLt[tid]= Ltb[nr];
      bCHg[tid]= Hgb[nr];  bCHt[tid]= Htb[nr];
      bUL[tid] = Lub[nr];  bUH[tid] = Hub[nr];
    }
    for (int u=tid; u<BPT*256; u+=NTH){
      const int b=u>>8, i=u&255;
      st_h[b][i]  = h0[(team*BPT+b)*256+i];
      st_o[b][i]  = 0.f;
      st_zh[b][i] = 0.f;
      st_zl[b][i] = 0.f;
    }
  }
  __syncthreads();

  u64* actT = act_base + (size_t)team*4096;   // 32KB/team; 2 x 1024-word buffers
  unsigned kst = 0;
  const bool wr0 = (j == 0);                  // only WG 0 writes out[]

  // C-cell: rows [8j,8j+8): units u<8 gate rows, u>=8 tanh rows. K=512=[o|hid].
  // Exchange word per (b,n): {f16 g, f16 T, tag}.
  auto cstage = [&](float (*WG)[520], float (*WT)[520], float* bG, float* bT,
                    float (*hid)[256], bool wout, int tt){
    const unsigned tag = kst + 1u;
    u64* buf = actT + (kst & 1u)*1024;
    WGBAR();                                   // prev-stage state updates visible
    const int u = tid>>4, kk = tid&15, r = u&7;
    const bool isT = (u>=8);
    const float* wr = isT? WT[r] : WG[r];
    float a0=0.f, a1=0.f;
    #pragma unroll
    for (int i=0;i<16;i++){
      const float w = wr[kk+16*i];
      a0 += w*st_o[0][kk+16*i];
      a1 += w*st_o[1][kk+16*i];
    }
    #pragma unroll
    for (int i=0;i<16;i++){
      const float w = wr[256+kk+16*i];
      a0 += w*hid[0][kk+16*i];
      a1 += w*hid[1][kk+16*i];
    }
    a0 += __shfl_xor(a0,1); a0 += __shfl_xor(a0,2); a0 += __shfl_xor(a0,4); a0 += __shfl_xor(a0,8);
    a1 += __shfl_xor(a1,1); a1 += __shfl_xor(a1,2); a1 += __shfl_xor(a1,4); a1 += __shfl_xor(a1,8);
    if (kk==0){ exvA[u][0] = a0; exvA[u][1] = a1; }
    WGBAR();
    if (tid < 16){                             // pack lanes: bias + activations + swap
      const int b = tid&1, rr = tid>>1;
      const float g = sigf (exvA[rr][b]   + bG[rr]);
      const float T = ftanh(exvA[8+rr][b] + bT[rr]);
      swpw(&buf[b*256 + j*8 + rr], packh(g, T, tag));
    }
    u64 w0, w1;
    for(;;){
      w0 = ldw(&buf[tid]); w1 = ldw(&buf[256+tid]);
      if ((unsigned)(w0>>32) >= tag && (unsigned)(w1>>32) >= tag) break;
      __builtin_amdgcn_s_sleep(1);
    }
    const float2 gt0 = upk2((unsigned)w0);
    const float2 gt1 = upk2((unsigned)w1);
    const float o0 = gt0.x*gt0.y + (1.f-gt0.x)*st_o[0][tid];
    const float o1 = gt1.x*gt1.y + (1.f-gt1.x)*st_o[1][tid];
    st_o[0][tid] = o0;
    st_o[1][tid] = o1;
    if (wout && wr0){
      out[((size_t)(team*BPT+0)*SEQ + tt)*256 + tid] = o0;
      out[((size_t)(team*BPT+1)*SEQ + tt)*256 + tid] = o1;
    }
    kst++;
  };

  // U-cell: 8 rows/WG, 32-lane units, K=256 over st_o; dst = tanh(pre).
  // Exchange word per n: {f16 v_b0, f16 v_b1, tag}.
  auto ustage = [&](float (*W)[264], float* bU, float (*dst)[256]){
    const unsigned tag = kst + 1u;
    u64* buf = actT + (kst & 1u)*1024;
    WGBAR();
    const int u = tid>>5, kk = tid&31;
    const float* wr = W[u];
    float a0=0.f, a1=0.f;
    #pragma unroll
    for (int i=0;i<8;i++){
      const float w = wr[kk+32*i];
      a0 += w*st_o[0][kk+32*i];
      a1 += w*st_o[1][kk+32*i];
    }
    a0 += __shfl_xor(a0,1); a0 += __shfl_xor(a0,2); a0 += __shfl_xor(a0,4); a0 += __shfl_xor(a0,8); a0 += __shfl_xor(a0,16);
    a1 += __shfl_xor(a1,1); a1 += __shfl_xor(a1,2); a1 += __shfl_xor(a1,4); a1 += __shfl_xor(a1,8); a1 += __shfl_xor(a1,16);
    if (kk==0){ exvA[u][0] = a0; exvA[u][1] = a1; }
    WGBAR();
    if (tid < 8){
      const float v0 = ftanh(exvA[tid][0] + bU[tid]);
      const float v1 = ftanh(exvA[tid][1] + bU[tid]);
      swpw(&buf[j*8 + tid], packh(v0, v1, tag));
    }
    u64 w0;
    for(;;){
      w0 = ldw(&buf[tid]);
      if ((unsigned)(w0>>32) >= tag) break;
      __builtin_amdgcn_s_sleep(1);
    }
    const float2 v = upk2((unsigned)w0);
    dst[0][tid] = v.x;
    dst[1][tid] = v.y;
    kst++;
  };

  float px0 = x[((size_t)(team*BPT+0)*SEQ + 0)*256 + tid];
  float px1 = x[((size_t)(team*BPT+1)*SEQ + 0)*256 + tid];

  #pragma unroll 1
  for (int t=0; t<SEQ; ++t){
    // ---- GRU stage. Exchange word per (b,n): {f16 n_gate, f16 z_gate, tag} ----
    {
      const unsigned tag = kst + 1u;
      u64* buf = actT + (kst & 1u)*1024;
      WGBAR();
      xst[0][tid] = px0;
      xst[1][tid] = px1;
      WGBAR();
      const int u = tid>>4, kk = tid&15, r = u&7;
      { // pass1: u<8 r-rows, u>=8 z-rows; K=512=[x|h]
        const float* wr = wgRZ[u];
        float a0=0.f, a1=0.f;
        #pragma unroll
        for (int i=0;i<16;i++){
          const float w = wr[kk+16*i];
          a0 += w*xst[0][kk+16*i];
          a1 += w*xst[1][kk+16*i];
        }
        #pragma unroll
        for (int i=0;i<16;i++){
          const float w = wr[256+kk+16*i];
          a0 += w*st_h[0][kk+16*i];
          a1 += w*st_h[1][kk+16*i];
        }
        a0 += __shfl_xor(a0,1); a0 += __shfl_xor(a0,2); a0 += __shfl_xor(a0,4); a0 += __shfl_xor(a0,8);
        a1 += __shfl_xor(a1,1); a1 += __shfl_xor(a1,2); a1 += __shfl_xor(a1,4); a1 += __shfl_xor(a1,8);
        if (kk==0){ exvA[u][0] = a0; exvA[u][1] = a1; }
      }
      { // pass2: u<8 xn rows (src=x), u>=8 hn rows (src=h); K=256
        const bool isH = (u>=8);
        const float* wr = isH? wgN[r] : wgX[r];
        float (*src)[256] = isH? st_h : xst;
        float a0=0.f, a1=0.f;
        #pragma unroll
        for (int i=0;i<16;i++){
          const float w = wr[kk+16*i];
          a0 += w*src[0][kk+16*i];
          a1 += w*src[1][kk+16*i];
        }
        a0 += __shfl_xor(a0,1); a0 += __shfl_xor(a0,2); a0 += __shfl_xor(a0,4); a0 += __shfl_xor(a0,8);
        a1 += __shfl_xor(a1,1); a1 += __shfl_xor(a1,2); a1 += __shfl_xor(a1,4); a1 += __shfl_xor(a1,8);
        if (kk==0){ exvB[u][0] = a0; exvB[u][1] = a1; }
      }
      WGBAR();
      if (tid < 16){                            // pack lanes: full gate math + swap
        const int b = tid&1, rr = tid>>1;
        const float pr = exvA[rr][b]   + bR[rr];
        const float pz = exvA[8+rr][b] + bZ[rr];
        const float xn = exvB[rr][b]   + bX[rr];
        const float hn = exvB[8+rr][b] + bN[rr];
        const float rg = sigf(pr);
        const float zg = sigf(pz);
        const float ng = ftanh(xn + rg*hn);
        swpw(&buf[b*256 + j*8 + rr], packh(ng, zg, tag));
      }
      u64 w0, w1;
      for(;;){
        w0 = ldw(&buf[tid]); w1 = ldw(&buf[256+tid]);
        if ((unsigned)(w0>>32) >= tag && (unsigned)(w1>>32) >= tag) break;
        __builtin_amdgcn_s_sleep(1);
      }
      const float2 nz0 = upk2((unsigned)w0);
      const float2 nz1 = upk2((unsigned)w1);
      const float h0v = (1.f-nz0.y)*nz0.x + nz0.y*st_h[0][tid];
      const float h1v = (1.f-nz1.y)*nz1.x + nz1.y*st_h[1][tid];
      st_h[0][tid] = h0v;  st_o[0][tid] = h0v;
      st_h[1][tid] = h1v;  st_o[1][tid] = h1v;
      if (t == SEQ-1 && wr0){
        out[(size_t)NB*SEQ*256 + (team*BPT+0)*256 + tid] = h0v;
        out[(size_t)NB*SEQ*256 + (team*BPT+1)*256 + tid] = h1v;
      }
      if (t+1 < SEQ){
        px0 = x[((size_t)(team*BPT+0)*SEQ + (t+1))*256 + tid];
        px1 = x[((size_t)(team*BPT+1)*SEQ + (t+1))*256 + tid];
      }
      kst++;
    }
    // ---- refinement: 2 H-cycles of (3x L-cell, U_L, H-cell, U_H) ----
    #pragma unroll 1
    for (int c=0;c<2;c++){
      cstage(wclG,wclT,bCLg,bCLt,st_zh,false,t);
      cstage(wclG,wclT,bCLg,bCLt,st_zh,false,t);
      cstage(wclG,wclT,bCLg,bCLt,st_zh,false,t);
      ustage(wul,bUL,st_zl);
      cstage(wchG,wchT,bCHg,bCHt,st_zl,(c==1),t);
      ustage(wuh,bUH,st_zh);
    }
  }
}

extern "C" void kernel_launch(void* const* d_in, const int* in_sizes, int n_in,
                              void* d_out, int out_size, void* d_ws, size_t ws_size,
                              hipStream_t stream)
{
  // ws: tagged act buffers, 32KB per team (2 x 1024 u64). Zeroed every launch
  // (tags must start below 1; harness poisons 0xAA once).
  (void)hipMemsetAsync(d_ws, 0, (size_t)TEAMS*4096*sizeof(u64), stream);
  u64* act = (u64*)d_ws;

  dim3 grid(TEAMS*WPT), block(NTH);
  hipLaunchKernelGGL(trm_kernel, grid, block, 0, stream,
    (const float*)d_in[0],  (const float*)d_in[1],
    (const float*)d_in[2],  (const float*)d_in[3],
    (const float*)d_in[4],  (const float*)d_in[5],
    (const float*)d_in[6],  (const float*)d_in[7],
    (const float*)d_in[8],  (const float*)d_in[9],
    (const float*)d_in[10], (const float*)d_in[11],
    (const float*)d_in[12], (const float*)d_in[13],
    (const float*)d_in[14], (const float*)d_in[15],
    (const float*)d_in[16], (const float*)d_in[17],
    (float*)d_out, act);
}

// Round 12
// 87035.974 us; speedup vs baseline: 3.3795x; 1.1247x over previous
//
#include <hip/hip_runtime.h>
#include <math.h>

// HierarchicalRecursiveTRM on MI355X — round 12.
// Base = round 11 (97.9ms): 8 teams x (2 batches, 32 WGs), f32 weights in LDS,
// producers publish f16-pair payloads via no-return atomic_exchange (MALL-
// resident), consumers poll tag-embedded words.
// Changes:
//  1. GRU off the critical path: GRU(t+1) is produced DURING L1(t) (hidden
//     under L1's exchange wait) into a dedicated 2-slot ring; the GRU stage
//     at t is a pre-satisfied poll. 12 serial exchanges/t instead of 13.
//  2. Fused 16B detection: both batches' words interleaved (buf[2n],buf[2n+1]),
//     consumer polls one global_load_dwordx4 sc0 sc1 (single MALL RT).

#define NB   16
#define SEQ  4096
#define TEAMS 8
#define WPT  32
#define BPT  2
#define NTH  256

typedef unsigned long long u64;
typedef unsigned u32x4 __attribute__((ext_vector_type(4)));

__device__ __forceinline__ float fexp(float v){ return __builtin_amdgcn_exp2f(v*1.44269504089f); }
__device__ __forceinline__ float sigf(float v){ return __builtin_amdgcn_rcpf(1.f + fexp(-v)); }
__device__ __forceinline__ float ftanh(float v){ return 2.f*sigf(2.f*v) - 1.f; }

// producer: no-return atomic swap — commits at the coherence-point atomic unit
__device__ __forceinline__ void swpw(u64* p, u64 v){
  (void)__hip_atomic_exchange(p, v, __ATOMIC_RELAXED, __HIP_MEMORY_SCOPE_AGENT);
}
// consumer: relaxed agent load (single-word poll, U-stages)
__device__ __forceinline__ u64 ldw(const u64* p){
  return __hip_atomic_load(p, __ATOMIC_RELAXED, __HIP_MEMORY_SCOPE_AGENT);
}

// f16x2 pack/unpack
typedef _Float16 h2f __attribute__((ext_vector_type(2)));
typedef __fp16   h2p __attribute__((ext_vector_type(2)));
union H2U { h2f f; h2p p; unsigned u; };
__device__ __forceinline__ unsigned pk2(float lo, float hi){
  H2U t; t.p = __builtin_amdgcn_cvt_pkrtz(lo, hi); return t.u;
}
__device__ __forceinline__ float2 upk2(unsigned w){
  H2U t; t.u = w; float2 r; r.x = (float)t.f.x; r.y = (float)t.f.y; return r;
}
__device__ __forceinline__ u64 packh(float lo, float hi, unsigned tag){
  return ((u64)tag<<32) | (u64)pk2(lo, hi);
}

// fused 16B poll: two adjacent tagged words in ONE dwordx4 sc0sc1 load
__device__ __forceinline__ void poll2x(const u64* p, unsigned tag,
                                       unsigned &lo0, unsigned &lo1){
  u32x4 v;
  for(;;){
    asm volatile("global_load_dwordx4 %0, %1, off sc0 sc1\n\ts_waitcnt vmcnt(0)"
                 : "=&v"(v) : "v"(p) : "memory");
    if (v.y >= tag && v.w >= tag) break;
    __builtin_amdgcn_s_sleep(1);
  }
  lo0 = v.x; lo1 = v.z;
}

// Raw WG barrier: LDS ordering only, no vmcnt drain (swaps fly free).
#define WGBAR() asm volatile("s_waitcnt lgkmcnt(0)\n\ts_barrier" ::: "memory")

extern "C" __global__ __launch_bounds__(NTH, 1)
void trm_kernel(const float* __restrict__ x,   const float* __restrict__ h0,
                const float* __restrict__ wih, const float* __restrict__ whh,
                const float* __restrict__ bih, const float* __restrict__ bhh,
                const float* __restrict__ Lgw, const float* __restrict__ Lgb,
                const float* __restrict__ Ltw, const float* __restrict__ Ltb,
                const float* __restrict__ Luw, const float* __restrict__ Lub,
                const float* __restrict__ Hgw, const float* __restrict__ Hgb,
                const float* __restrict__ Htw, const float* __restrict__ Htb,
                const float* __restrict__ Huw, const float* __restrict__ Hub,
                float* __restrict__ out, u64* __restrict__ act_base)
{
  const int team = blockIdx.x & (TEAMS-1);
  const int j    = blockIdx.x / TEAMS;       // 0..31 slice id within team
  const int tid  = threadIdx.x;

  __shared__ float wgRZ[16][520];
  __shared__ float wgX[8][264];
  __shared__ float wgN[8][264];
  __shared__ float wclG[8][520], wclT[8][520];
  __shared__ float wchG[8][520], wchT[8][520];
  __shared__ float wul[8][264],  wuh[8][264];
  __shared__ float xst [BPT][256];
  __shared__ float st_o [BPT][256];
  __shared__ float st_zh[BPT][256];
  __shared__ float st_zl[BPT][256];
  __shared__ float st_h [BPT][256];
  __shared__ float exvA[16][2], exvC[16][2], exvD[16][2];
  __shared__ float bR[8],bZ[8],bX[8],bN[8],bCLg[8],bCLt[8],bCHg[8],bCHt[8],bUL[8],bUH[8];

  // ---------- one-time weight staging ----------
  {
    const int k = tid;
    for (int r=0;r<8;r++){
      const int nr = j*8+r;
      wgRZ[r][k]       = wih[(size_t)nr*256+k];
      wgRZ[r][256+k]   = whh[(size_t)nr*256+k];
      wgRZ[8+r][k]     = wih[(size_t)(256+nr)*256+k];
      wgRZ[8+r][256+k] = whh[(size_t)(256+nr)*256+k];
      wgX[r][k] = wih[(size_t)(512+nr)*256+k];
      wgN[r][k] = whh[(size_t)(512+nr)*256+k];
      wclG[r][k] = Lgw[(size_t)nr*512+k];  wclG[r][256+k] = Lgw[(size_t)nr*512+256+k];
      wclT[r][k] = Ltw[(size_t)nr*512+k];  wclT[r][256+k] = Ltw[(size_t)nr*512+256+k];
      wchG[r][k] = Hgw[(size_t)nr*512+k];  wchG[r][256+k] = Hgw[(size_t)nr*512+256+k];
      wchT[r][k] = Htw[(size_t)nr*512+k];  wchT[r][256+k] = Htw[(size_t)nr*512+256+k];
      wul[r][k] = Luw[(size_t)nr*256+k];
      wuh[r][k] = Huw[(size_t)nr*256+k];
    }
    if (tid<8){
      const int nr = j*8+tid;
      bR[tid]  = bih[nr]     + bhh[nr];
      bZ[tid]  = bih[256+nr] + bhh[256+nr];
      bX[tid]  = bih[512+nr];
      bN[tid]  = bhh[512+nr];
      bCLg[tid]= Lgb[nr];  bCLt[tid]= Ltb[nr];
      bCHg[tid]= Hgb[nr];  bCHt[tid]= Htb[nr];
      bUL[tid] = Lub[nr];  bUH[tid] = Hub[nr];
    }
    st_h[0][tid]  = h0[(team*BPT+0)*256+tid];
    st_h[1][tid]  = h0[(team*BPT+1)*256+tid];
    st_o[0][tid]  = 0.f;  st_o[1][tid]  = 0.f;
    st_zh[0][tid] = 0.f;  st_zh[1][tid] = 0.f;
    st_zl[0][tid] = 0.f;  st_zl[1][tid] = 0.f;
    xst[0][tid] = x[((size_t)(team*BPT+0)*SEQ + 0)*256 + tid];
    xst[1][tid] = x[((size_t)(team*BPT+1)*SEQ + 0)*256 + tid];
  }
  __syncthreads();

  u64* actT = act_base + (size_t)team*4096;   // [0,2048): 2 refine bufs; [2048,3072): GRU ring
  u64* gb   = actT + 2048;
  unsigned kst = 0;
  const bool wr0 = (j == 0);

  // GRU produce for step `step` (reads xst = x(step), st_h = h(step-1)):
  // publishes {f16 n_gate, f16 z_gate, tag=step+1} into gb slot (step&1).
  auto gru_produce = [&](int step){
    const unsigned gt = (unsigned)step + 1u;
    u64* g = gb + (size_t)(step & 1)*512;
    const int u = tid>>4, kk = tid&15, r = u&7;
    { // pass1: u<8 r-rows, u>=8 z-rows; K=512=[x|h]
      const float* wr = wgRZ[u];
      float a0=0.f, a1=0.f;
      #pragma unroll
      for (int i=0;i<16;i++){
        const float w = wr[kk+16*i];
        a0 += w*xst[0][kk+16*i];
        a1 += w*xst[1][kk+16*i];
      }
      #pragma unroll
      for (int i=0;i<16;i++){
        const float w = wr[256+kk+16*i];
        a0 += w*st_h[0][kk+16*i];
        a1 += w*st_h[1][kk+16*i];
      }
      a0 += __shfl_xor(a0,1); a0 += __shfl_xor(a0,2); a0 += __shfl_xor(a0,4); a0 += __shfl_xor(a0,8);
      a1 += __shfl_xor(a1,1); a1 += __shfl_xor(a1,2); a1 += __shfl_xor(a1,4); a1 += __shfl_xor(a1,8);
      if (kk==0){ exvC[u][0] = a0; exvC[u][1] = a1; }
    }
    { // pass2: u<8 xn rows (src=x), u>=8 hn rows (src=h); K=256
      const bool isH = (u>=8);
      const float* wr = isH? wgN[r] : wgX[r];
      float (*src)[256] = isH? st_h : xst;
      float a0=0.f, a1=0.f;
      #pragma unroll
      for (int i=0;i<16;i++){
        const float w = wr[kk+16*i];
        a0 += w*src[0][kk+16*i];
        a1 += w*src[1][kk+16*i];
      }
      a0 += __shfl_xor(a0,1); a0 += __shfl_xor(a0,2); a0 += __shfl_xor(a0,4); a0 += __shfl_xor(a0,8);
      a1 += __shfl_xor(a1,1); a1 += __shfl_xor(a1,2); a1 += __shfl_xor(a1,4); a1 += __shfl_xor(a1,8);
      if (kk==0){ exvD[u][0] = a0; exvD[u][1] = a1; }
    }
    WGBAR();
    if (tid < 16){
      const int b = tid&1, rr = tid>>1;
      const float pr = exvC[rr][b]   + bR[rr];
      const float pz = exvC[8+rr][b] + bZ[rr];
      const float xn = exvD[rr][b]   + bX[rr];
      const float hn = exvD[8+rr][b] + bN[rr];
      const float rg = sigf(pr);
      const float zg = sigf(pz);
      const float ng = ftanh(xn + rg*hn);
      swpw(&g[(size_t)(j*8+rr)*2 + b], packh(ng, zg, gt));
    }
  };

  // C-cell: rows [8j,8j+8): units u<8 gate rows, u>=8 tanh rows. K=512=[o|hid].
  // Word layout: buf[n*2+b] = {f16 g, f16 T, tag}. pg: also produce GRU(tt+1).
  auto cstage = [&](float (*WG)[520], float (*WT)[520], float* bG, float* bT,
                    float (*hid)[256], bool wout, bool pg, int tt){
    const unsigned tag = kst + 1u;
    u64* buf = actT + (kst & 1u)*1024;
    WGBAR();                                   // prev-stage state updates visible
    const int u = tid>>4, kk = tid&15, r = u&7;
    const bool isT = (u>=8);
    const float* wr = isT? WT[r] : WG[r];
    float a0=0.f, a1=0.f;
    #pragma unroll
    for (int i=0;i<16;i++){
      const float w = wr[kk+16*i];
      a0 += w*st_o[0][kk+16*i];
      a1 += w*st_o[1][kk+16*i];
    }
    #pragma unroll
    for (int i=0;i<16;i++){
      const float w = wr[256+kk+16*i];
      a0 += w*hid[0][kk+16*i];
      a1 += w*hid[1][kk+16*i];
    }
    a0 += __shfl_xor(a0,1); a0 += __shfl_xor(a0,2); a0 += __shfl_xor(a0,4); a0 += __shfl_xor(a0,8);
    a1 += __shfl_xor(a1,1); a1 += __shfl_xor(a1,2); a1 += __shfl_xor(a1,4); a1 += __shfl_xor(a1,8);
    if (kk==0){ exvA[u][0] = a0; exvA[u][1] = a1; }
    WGBAR();
    if (tid < 16){
      const int b = tid&1, rr = tid>>1;
      const float g = sigf (exvA[rr][b]   + bG[rr]);
      const float T = ftanh(exvA[8+rr][b] + bT[rr]);
      swpw(&buf[(size_t)(j*8+rr)*2 + b], packh(g, T, tag));
    }
    if (pg) gru_produce(tt+1);                 // hidden under this stage's exchange wait
    unsigned lo0, lo1;
    poll2x(&buf[2*tid], tag, lo0, lo1);
    const float2 gt0 = upk2(lo0);
    const float2 gt1 = upk2(lo1);
    const float o0 = gt0.x*gt0.y + (1.f-gt0.x)*st_o[0][tid];
    const float o1 = gt1.x*gt1.y + (1.f-gt1.x)*st_o[1][tid];
    st_o[0][tid] = o0;
    st_o[1][tid] = o1;
    if (wout && wr0){
      out[((size_t)(team*BPT+0)*SEQ + tt)*256 + tid] = o0;
      out[((size_t)(team*BPT+1)*SEQ + tt)*256 + tid] = o1;
    }
    kst++;
  };

  // U-cell: 8 rows/WG, 32-lane units, K=256 over st_o; dst = tanh(pre).
  // Word per n: {f16 v_b0, f16 v_b1, tag} at buf[n].
  auto ustage = [&](float (*W)[264], float* bU, float (*dst)[256]){
    const unsigned tag = kst + 1u;
    u64* buf = actT + (kst & 1u)*1024;
    WGBAR();
    const int u = tid>>5, kk = tid&31;
    const float* wr = W[u];
    float a0=0.f, a1=0.f;
    #pragma unroll
    for (int i=0;i<8;i++){
      const float w = wr[kk+32*i];
      a0 += w*st_o[0][kk+32*i];
      a1 += w*st_o[1][kk+32*i];
    }
    a0 += __shfl_xor(a0,1); a0 += __shfl_xor(a0,2); a0 += __shfl_xor(a0,4); a0 += __shfl_xor(a0,8); a0 += __shfl_xor(a0,16);
    a1 += __shfl_xor(a1,1); a1 += __shfl_xor(a1,2); a1 += __shfl_xor(a1,4); a1 += __shfl_xor(a1,8); a1 += __shfl_xor(a1,16);
    if (kk==0){ exvA[u][0] = a0; exvA[u][1] = a1; }
    WGBAR();
    if (tid < 8){
      const float v0 = ftanh(exvA[tid][0] + bU[tid]);
      const float v1 = ftanh(exvA[tid][1] + bU[tid]);
      swpw(&buf[j*8 + tid], packh(v0, v1, tag));
    }
    u64 w0;
    for(;;){
      w0 = ldw(&buf[tid]);
      if ((unsigned)(w0>>32) >= tag) break;
      __builtin_amdgcn_s_sleep(1);
    }
    const float2 v = upk2((unsigned)w0);
    dst[0][tid] = v.x;
    dst[1][tid] = v.y;
    kst++;
  };

  // prologue: produce GRU(0) (tag 1, slot 0) from h0 and x(0)
  float px0 = x[((size_t)(team*BPT+0)*SEQ + 1)*256 + tid];
  float px1 = x[((size_t)(team*BPT+1)*SEQ + 1)*256 + tid];
  gru_produce(0);

  #pragma unroll 1
  for (int t=0; t<SEQ; ++t){
    // ---- GRU consume (pre-satisfied poll: produced >=11 stages ago) ----
    {
      WGBAR();                                 // prior U_H matvec reads of st_o done
      u64* g = gb + (size_t)(t & 1)*512;
      unsigned lo0, lo1;
      poll2x(&g[2*tid], (unsigned)(t+1), lo0, lo1);
      const float2 nz0 = upk2(lo0);
      const float2 nz1 = upk2(lo1);
      const float h0v = (1.f-nz0.y)*nz0.x + nz0.y*st_h[0][tid];
      const float h1v = (1.f-nz1.y)*nz1.x + nz1.y*st_h[1][tid];
      st_h[0][tid] = h0v;  st_o[0][tid] = h0v;
      st_h[1][tid] = h1v;  st_o[1][tid] = h1v;
      xst[0][tid] = px0;                       // x(t+1) for GRU produce at L1(t)
      xst[1][tid] = px1;
      if (t+2 < SEQ){
        px0 = x[((size_t)(team*BPT+0)*SEQ + (t+2))*256 + tid];
        px1 = x[((size_t)(team*BPT+1)*SEQ + (t+2))*256 + tid];
      }
      if (t == SEQ-1 && wr0){
        out[(size_t)NB*SEQ*256 + (team*BPT+0)*256 + tid] = h0v;
        out[(size_t)NB*SEQ*256 + (team*BPT+1)*256 + tid] = h1v;
      }
    }
    // ---- refinement: 2 H-cycles of (3x L-cell, U_L, H-cell, U_H) ----
    #pragma unroll 1
    for (int c=0;c<2;c++){
      cstage(wclG,wclT,bCLg,bCLt,st_zh,false,(c==0)&&(t+1<SEQ),t);  // L1 (+GRU(t+1))
      cstage(wclG,wclT,bCLg,bCLt,st_zh,false,false,t);
      cstage(wclG,wclT,bCLg,bCLt,st_zh,false,false,t);
      ustage(wul,bUL,st_zl);
      cstage(wchG,wchT,bCHg,bCHt,st_zl,(c==1),false,t);
      ustage(wuh,bUH,st_zh);
    }
  }
}

extern "C" void kernel_launch(void* const* d_in, const int* in_sizes, int n_in,
                              void* d_out, int out_size, void* d_ws, size_t ws_size,
                              hipStream_t stream)
{
  // ws: per-team 32KB = [2 x 1024 u64 refine bufs | 2 x 512 u64 GRU ring].
  // Zeroed every launch (tags must start below 1; harness poisons 0xAA once).
  (void)hipMemsetAsync(d_ws, 0, (size_t)TEAMS*4096*sizeof(u64), stream);
  u64* act = (u64*)d_ws;

  dim3 grid(TEAMS*WPT), block(NTH);
  hipLaunchKernelGGL(trm_kernel, grid, block, 0, stream,
    (const float*)d_in[0],  (const float*)d_in[1],
    (const float*)d_in[2],  (const float*)d_in[3],
    (const float*)d_in[4],  (const float*)d_in[5],
    (const float*)d_in[6],  (const float*)d_in[7],
    (const float*)d_in[8],  (const float*)d_in[9],
    (const float*)d_in[10], (const float*)d_in[11],
    (const float*)d_in[12], (const float*)d_in[13],
    (const float*)d_in[14], (const float*)d_in[15],
    (const float*)d_in[16], (const float*)d_in[17],
    (float*)d_out, act);
}